// Round 10
// baseline (246.821 us; speedup 1.0000x reference)
//
#include <hip/hip_runtime.h>
#include <hip/hip_bf16.h>
#include <cstdint>

// MHA with full attn-matrix output.  B=2 S=2048 D=1024 N=16 H=64.
// d_out = [out (B,S,D) fp32 | attn (B,N,S,S) fp32]

typedef __attribute__((ext_vector_type(4))) float f32x4;
typedef __attribute__((ext_vector_type(8))) short s16x8;
typedef __attribute__((ext_vector_type(8))) unsigned short us8;
typedef __attribute__((ext_vector_type(4))) unsigned short us4;

#define MFMA16(a, b, c) __builtin_amdgcn_mfma_f32_16x16x32_bf16((a), (b), (c), 0, 0, 0)
constexpr float L2E = 1.4426950408889634f;

__device__ __forceinline__ unsigned short f2bf(float f) {
  unsigned int u = __builtin_bit_cast(unsigned int, f);
  u += 0x7FFFu + ((u >> 16) & 1u);  // RNE
  return (unsigned short)(u >> 16);
}
__device__ __forceinline__ unsigned int cvtpk(float lo, float hi) {
  unsigned int r;
  asm("v_cvt_pk_bf16_f32 %0, %1, %2" : "=v"(r) : "v"(lo), "v"(hi));
  return r;
}
__device__ __forceinline__ s16x8 ldfrag(const unsigned short* p) {
  return __builtin_bit_cast(s16x8, *(const us8*)p);
}
// lds dest MUST be wave-uniform; per-lane part goes in g.
__device__ __forceinline__ void gload16(const void* g, void* l) {
  auto* gp = reinterpret_cast<const __attribute__((address_space(1))) unsigned int*>(
      reinterpret_cast<uintptr_t>(g));
  auto* lp = reinterpret_cast<__attribute__((address_space(3))) unsigned int*>(
      reinterpret_cast<uintptr_t>(l));
  __builtin_amdgcn_global_load_lds(gp, lp, 16, 0, 0);
}

// ---------------------------------------------------------------------------
// convert fp32 [4096][1024] -> bf16, granule-swizzled: kg' = (kg&~7)|((kg^m)&7)
// ---------------------------------------------------------------------------
__global__ __launch_bounds__(256) void convin_k(const float* __restrict__ s0,
                                                const float* __restrict__ s1,
                                                const float* __restrict__ s2,
                                                unsigned short* __restrict__ d0,
                                                unsigned short* __restrict__ d1,
                                                unsigned short* __restrict__ d2) {
  const float* s = blockIdx.y == 0 ? s0 : (blockIdx.y == 1 ? s1 : s2);
  unsigned short* d = blockIdx.y == 0 ? d0 : (blockIdx.y == 1 ? d1 : d2);
  int gid = blockIdx.x * 256 + threadIdx.x;
  int m = gid >> 7, kg = gid & 127;
  f32x4 a = *(const f32x4*)(s + (size_t)m * 1024 + kg * 8);
  f32x4 b = *(const f32x4*)(s + (size_t)m * 1024 + kg * 8 + 4);
  us8 o;
#pragma unroll
  for (int j = 0; j < 4; ++j) { o[j] = f2bf(a[j]); o[j + 4] = f2bf(b[j]); }
  int kgp = (kg & ~7) | ((kg ^ m) & 7);
  *(us8*)(d + (size_t)m * 1024 + kgp * 8) = o;
}

// ---------------------------------------------------------------------------
// transpose+convert weights: [1024][1024] f32 -> [c][r] bf16, swizzled.
// ---------------------------------------------------------------------------
__global__ __launch_bounds__(256) void convw_k(const float* __restrict__ w0,
                                               const float* __restrict__ w1,
                                               const float* __restrict__ w2,
                                               const float* __restrict__ w3,
                                               unsigned short* __restrict__ o0,
                                               unsigned short* __restrict__ o1,
                                               unsigned short* __restrict__ o2,
                                               unsigned short* __restrict__ o3) {
  const float* W = blockIdx.y == 0 ? w0 : (blockIdx.y == 1 ? w1 : (blockIdx.y == 2 ? w2 : w3));
  unsigned short* O = blockIdx.y == 0 ? o0 : (blockIdx.y == 1 ? o1 : (blockIdx.y == 2 ? o2 : o3));
  const int t = threadIdx.x;
  const int r0 = (blockIdx.x & 15) * 64, c0 = (blockIdx.x >> 4) * 64;
  __shared__ float tile[64][65];
  {
    int r = t >> 2, cq = (t & 3) * 16;
#pragma unroll
    for (int j = 0; j < 4; ++j) {
      f32x4 v = *(const f32x4*)(W + (size_t)(r0 + r) * 1024 + c0 + cq + j * 4);
#pragma unroll
      for (int e = 0; e < 4; ++e) tile[r][cq + j * 4 + e] = v[e];
    }
  }
  __syncthreads();
  int orow = t >> 2;
  int gr = c0 + orow;
#pragma unroll
  for (int gi = 0; gi < 2; ++gi) {
    int dl = (t & 3) * 16 + gi * 8;
    us8 o;
#pragma unroll
    for (int j = 0; j < 8; ++j) o[j] = f2bf(tile[dl + j][orow]);
    int kg = (r0 + dl) >> 3;
    int kgp = (kg & ~7) | ((kg ^ gr) & 7);
    *(us8*)(O + (size_t)gr * 1024 + kgp * 8) = o;
  }
}

// ---------------------------------------------------------------------------
// Fused QKV projection GEMM: z in {0,1,2} selects (A, W, dst).
// z==0: Q -> MFMA-fragment order (scaled 1/8), same mapping as K.
// z==1: K -> MFMA-fragment order: per head, per 64-row tile:
//        off = fc*1024 + half*512 + lane*8 + j   where fc=(s>>4)&3,
//        half=h>>5, lane=((h>>3)&3)*16 + (s&15), j=h&7.
// z==2: V -> per-64-tile layout [h][g^(h&7)][s&7] (DMA-stageable, proven).
// ---------------------------------------------------------------------------
__global__ __launch_bounds__(256) void qkv_gemm(
    const unsigned short* __restrict__ Aq, const unsigned short* __restrict__ Ak,
    const unsigned short* __restrict__ Av, const unsigned short* __restrict__ Bq,
    const unsigned short* __restrict__ Bk, const unsigned short* __restrict__ Bv,
    unsigned short* __restrict__ Oq, unsigned short* __restrict__ Ok,
    unsigned short* __restrict__ Ov) {
  const int z = blockIdx.z;
  const unsigned short* A = z == 0 ? Aq : (z == 1 ? Ak : Av);
  const unsigned short* Bt = z == 0 ? Bq : (z == 1 ? Bk : Bv);

  __shared__ __align__(16) unsigned short lds[16384];
  const int t = threadIdx.x, w = t >> 6, lane = t & 63;
  const int lr = lane & 15, lg = lane >> 4;
  const int wr = (w >> 1) * 64, wc = (w & 1) * 64;
  const int m0 = blockIdx.y * 128, n0 = blockIdx.x * 128;
  const int srow = w * 32 + (lane >> 3), sg = lane & 7;

  f32x4 acc[4][4];
#pragma unroll
  for (int i = 0; i < 4; ++i)
#pragma unroll
    for (int j = 0; j < 4; ++j) acc[i][j] = (f32x4){0.f, 0.f, 0.f, 0.f};

  for (int k0 = 0; k0 < 1024; k0 += 64) {
#pragma unroll
    for (int q = 0; q < 4; ++q)
      gload16(A + (size_t)(m0 + srow + q * 8) * 1024 + k0 + sg * 8,
              &lds[(w * 32 + q * 8) * 64]);
#pragma unroll
    for (int q = 0; q < 4; ++q)
      gload16(Bt + (size_t)(n0 + srow + q * 8) * 1024 + k0 + sg * 8,
              &lds[8192 + (w * 32 + q * 8) * 64]);
    __syncthreads();
#pragma unroll
    for (int r2 = 0; r2 < 2; ++r2) {
      const int koff = ((r2 * 4 + lg) ^ (lr & 7)) * 8;
      s16x8 af[4], bfr[4];
#pragma unroll
      for (int x = 0; x < 4; ++x) af[x] = ldfrag(&lds[(wr + x * 16 + lr) * 64 + koff]);
#pragma unroll
      for (int x = 0; x < 4; ++x) bfr[x] = ldfrag(&lds[8192 + (wc + x * 16 + lr) * 64 + koff]);
#pragma unroll
      for (int am = 0; am < 4; ++am)
#pragma unroll
        for (int bn = 0; bn < 4; ++bn) acc[am][bn] = MFMA16(af[am], bfr[bn], acc[am][bn]);
    }
    __syncthreads();
  }

  if (z < 2) {
    unsigned short* C = z == 0 ? Oq : Ok;
    const float scale = z == 0 ? 0.125f : 1.0f;
#pragma unroll
    for (int am = 0; am < 4; ++am)
#pragma unroll
      for (int bn = 0; bn < 4; ++bn)
#pragma unroll
        for (int i = 0; i < 4; ++i) {
          int gr = m0 + wr + am * 16 + lg * 4 + i;  // b*S + s
          int gc = n0 + wc + bn * 16 + lr;          // n*H + h
          int bb = gr >> 11, ss = gr & 2047;
          int nn = gc >> 6, hh = gc & 63;
          size_t base = ((size_t)(bb * 16 + nn)) * 131072 + (size_t)(ss >> 6) * 4096;
          int off = ((ss >> 4) & 3) * 1024 + (hh >> 5) * 512 +
                    (((hh >> 3) & 3) * 16 + (ss & 15)) * 8 + (hh & 7);
          C[base + off] = f2bf(acc[am][bn][i] * scale);
        }
  } else {
#pragma unroll
    for (int am = 0; am < 4; ++am)
#pragma unroll
      for (int bn = 0; bn < 4; ++bn)
#pragma unroll
        for (int i = 0; i < 4; ++i) {
          int gr = m0 + wr + am * 16 + lg * 4 + i;
          int gc = n0 + wc + bn * 16 + lr;
          int bb = gr >> 11, ss = gr & 2047;
          int nn = gc >> 6, hh = gc & 63;
          size_t base = ((size_t)(bb * 16 + nn)) * 131072 + (size_t)(ss >> 6) * 4096;
          int off = hh * 64 + (((((ss >> 3) & 7) ^ (hh & 7))) << 3) + (ss & 7);
          Ov[base + off] = f2bf(acc[am][bn][i]);
        }
  }
}

// ---------------------------------------------------------------------------
// Wo GEMM: out[4096,1024] fp32 = ctx(bf16 swz) * WoT.  128x64 tile -> 512 blk.
// ---------------------------------------------------------------------------
__global__ __launch_bounds__(256) void gemmWo(const unsigned short* __restrict__ A,
                                              const unsigned short* __restrict__ Bt,
                                              float* __restrict__ C) {
  __shared__ __align__(16) unsigned short lds[12288];
  const int t = threadIdx.x, w = t >> 6, lane = t & 63;
  const int lr = lane & 15, lg = lane >> 4;
  const int wr = (w >> 1) * 64, wc = (w & 1) * 32;
  const int m0 = blockIdx.y * 128, n0 = blockIdx.x * 64;

  f32x4 acc[4][2];
#pragma unroll
  for (int i = 0; i < 4; ++i)
#pragma unroll
    for (int j = 0; j < 2; ++j) acc[i][j] = (f32x4){0.f, 0.f, 0.f, 0.f};

  for (int k0 = 0; k0 < 1024; k0 += 64) {
#pragma unroll
    for (int q = 0; q < 4; ++q)
      gload16(A + (size_t)(m0 + w * 32 + q * 8 + (lane >> 3)) * 1024 + k0 + (lane & 7) * 8,
              &lds[(w * 32 + q * 8) * 64]);
#pragma unroll
    for (int q = 0; q < 2; ++q)
      gload16(Bt + (size_t)(n0 + w * 16 + q * 8 + (lane >> 3)) * 1024 + k0 + (lane & 7) * 8,
              &lds[8192 + (w * 16 + q * 8) * 64]);
    __syncthreads();
#pragma unroll
    for (int r2 = 0; r2 < 2; ++r2) {
      const int koff = ((r2 * 4 + lg) ^ (lr & 7)) * 8;
      s16x8 af[4], bfr[2];
#pragma unroll
      for (int x = 0; x < 4; ++x) af[x] = ldfrag(&lds[(wr + x * 16 + lr) * 64 + koff]);
#pragma unroll
      for (int x = 0; x < 2; ++x) bfr[x] = ldfrag(&lds[8192 + (wc + x * 16 + lr) * 64 + koff]);
#pragma unroll
      for (int am = 0; am < 4; ++am)
#pragma unroll
        for (int bn = 0; bn < 2; ++bn) acc[am][bn] = MFMA16(af[am], bfr[bn], acc[am][bn]);
    }
    __syncthreads();
  }
#pragma unroll
  for (int am = 0; am < 4; ++am)
#pragma unroll
    for (int bn = 0; bn < 2; ++bn)
#pragma unroll
      for (int i = 0; i < 4; ++i) {
        int gr = m0 + wr + am * 16 + lg * 4 + i;
        int gc = n0 + wc + bn * 16 + lr;
        C[(size_t)gr * 1024 + gc] = acc[am][bn][i];
      }
}

// ---------------------------------------------------------------------------
// Fused causal attention, swapped-QK.  Block=(b,head,64 q-rows), 4 waves.
// Q/K in fragment-order global layout (lane-contiguous 1KB bursts, no LDS).
// K software-pipelined into registers (2-state kA/kB).  Max-free softmax.
// V DMA-staged double-buffered.  attn stores are DELAYED one tile (carried
// in registers across the barrier) so the barrier's vmcnt(0) drain finds
// them already retired -- stores overlap the next tile's compute.
// ---------------------------------------------------------------------------
__global__ __launch_bounds__(256) void attn_k(const unsigned short* __restrict__ qw,
                                              const unsigned short* __restrict__ kw,
                                              const unsigned short* __restrict__ vw,
                                              float* __restrict__ attn,
                                              unsigned short* __restrict__ ctx) {
  constexpr int S = 2048, N = 16;
  const int flat = blockIdx.x;
  const int nf = (flat & 7) * 128 + (flat >> 3);  // XCD-chunked
  const int qt = nf & 31, hd = (nf >> 5) & 15, b = nf >> 9;
  const int qbase = qt * 64;
  const int t = threadIdx.x, w = t >> 6, lane = t & 63;
  const int lr = lane & 15, lg = lane >> 4;
  const size_t headoff = ((size_t)(b * N + hd)) * S * 64;
  const unsigned short* qh = qw + headoff;  // fragment-order tiles
  const unsigned short* kh = kw + headoff;  // fragment-order tiles
  const unsigned short* vh = vw + headoff;  // tiled V
  float* attn_h = attn + ((size_t)(b * N + hd)) * S * S;
  const int qrow = qbase + w * 16 + lr;

  __shared__ __align__(16) unsigned short ldsv[2][4096];
  __shared__ __align__(16) float twbuf[4][16][72];

  s16x8 qf0 = ldfrag(qh + (size_t)qt * 4096 + w * 1024 + lane * 8);
  s16x8 qf1 = ldfrag(qh + (size_t)qt * 4096 + w * 1024 + 512 + lane * 8);

  s16x8 kA[8], kB[8];
  auto loadK = [&](s16x8(&kf)[8], int kt) {
    const unsigned short* kb = kh + (size_t)kt * 4096;
#pragma unroll
    for (int fc = 0; fc < 4; ++fc) {
      kf[fc * 2] = ldfrag(kb + fc * 1024 + lane * 8);
      kf[fc * 2 + 1] = ldfrag(kb + fc * 1024 + 512 + lane * 8);
    }
  };

  // ---------------- pass 1: per-row sum of exp (max-free, pipelined) -------
  float lsum = 0.f;
  auto p1body = [&](s16x8(&kf)[8], int kt) {
    float ts = 0.f;
#pragma unroll
    for (int fc = 0; fc < 4; ++fc) {
      f32x4 a = (f32x4){0.f, 0.f, 0.f, 0.f};
      a = MFMA16(kf[fc * 2], qf0, a);
      a = MFMA16(kf[fc * 2 + 1], qf1, a);
      if (kt == qt) {
#pragma unroll
        for (int i = 0; i < 4; ++i)
          if (qbase + fc * 16 + lg * 4 + i > qrow) a[i] = -3.0e38f;
      }
#pragma unroll
      for (int i = 0; i < 4; ++i) ts += __builtin_amdgcn_exp2f(a[i] * L2E);
    }
    lsum += ts;
  };
  loadK(kA, 0);
  {
    int kt = 0;
    while (true) {
      if (kt < qt) loadK(kB, kt + 1);
      p1body(kA, kt);
      if (++kt > qt) break;
      if (kt < qt) loadK(kA, kt + 1);
      p1body(kB, kt);
      if (++kt > qt) break;
    }
  }
  lsum += __shfl_xor(lsum, 16);
  lsum += __shfl_xor(lsum, 32);
  const float c0 = -__builtin_amdgcn_logf(lsum);  // v_log_f32=log2; p=exp2(s*L2E+c0)

  // ---------------- pass 2: attn write + PV (pipelined, delayed stores) ----
  f32x4 accpv[4];
#pragma unroll
  for (int i = 0; i < 4; ++i) accpv[i] = (f32x4){0.f, 0.f, 0.f, 0.f};
  const int src0 = lr + 32 * (lg & 1), src1 = src0 + 16;
  const bool hiFc = (lg >> 1) & 1;

  f32x4 pend[4];  // tile-(kt-1) transposed attn rows, carried across barrier

  auto vdma = [&](int kt, int buf) {
    const unsigned short* vsrc = vh + (size_t)kt * 4096;
    gload16(vsrc + (w * 128 + lane) * 8, &ldsv[buf][w * 1024]);
    gload16(vsrc + (w * 128 + 64 + lane) * 8, &ldsv[buf][w * 1024 + 512]);
  };
  auto flushA = [&](int kt0) {
#pragma unroll
    for (int rr = 0; rr < 4; ++rr)
      *(f32x4*)(attn_h + (size_t)(qbase + w * 16 + lg * 4 + rr) * S + kt0 * 64 + lr * 4) =
          pend[rr];
  };

  auto p2body = [&](s16x8(&kf)[8], int kt) {
    const int cb = kt & 1;
    f32x4 s[4];
#pragma unroll
    for (int fc = 0; fc < 4; ++fc) {
      f32x4 a = (f32x4){0.f, 0.f, 0.f, 0.f};
      a = MFMA16(kf[fc * 2], qf0, a);
      a = MFMA16(kf[fc * 2 + 1], qf1, a);
      s[fc] = a;
    }
    unsigned int Wlo[4], Whi[4];
#pragma unroll
    for (int fc = 0; fc < 4; ++fc) {
      f32x4 p;
#pragma unroll
      for (int i = 0; i < 4; ++i)
        p[i] = __builtin_amdgcn_exp2f(__builtin_fmaf(s[fc][i], L2E, c0));
      if (kt == qt) {
#pragma unroll
        for (int i = 0; i < 4; ++i)
          if (qbase + fc * 16 + lg * 4 + i > qrow) p[i] = 0.0f;
      }
      *(f32x4*)&twbuf[w][lr][fc * 16 + lg * 4] = p;
      Wlo[fc] = cvtpk(p[0], p[1]);
      Whi[fc] = cvtpk(p[2], p[3]);
    }
#pragma unroll
    for (int ks = 0; ks < 2; ++ks) {
      unsigned int d0a = __shfl((int)Wlo[2 * ks], src0, 64);
      unsigned int d0b = __shfl((int)Wlo[2 * ks + 1], src0, 64);
      unsigned int d1a = __shfl((int)Whi[2 * ks], src0, 64);
      unsigned int d1b = __shfl((int)Whi[2 * ks + 1], src0, 64);
      unsigned int d2a = __shfl((int)Wlo[2 * ks], src1, 64);
      unsigned int d2b = __shfl((int)Wlo[2 * ks + 1], src1, 64);
      unsigned int d3a = __shfl((int)Whi[2 * ks], src1, 64);
      unsigned int d3b = __shfl((int)Whi[2 * ks + 1], src1, 64);
      unsigned int pd[4] = {hiFc ? d0b : d0a, hiFc ? d1b : d1a,
                            hiFc ? d2b : d2a, hiFc ? d3b : d3a};
      s16x8 pa = __builtin_bit_cast(s16x8, *(us8*)pd);
#pragma unroll
      for (int hc = 0; hc < 4; ++hc) {
        s16x8 vb = ldfrag(&ldsv[cb][(hc * 16 + lr) * 64 + (((ks * 4 + lg) ^ (lr & 7)) << 3)]);
        accpv[hc] = MFMA16(pa, vb, accpv[hc]);
      }
    }
    // capture transposed rows into registers; global store happens next iter
#pragma unroll
    for (int rr = 0; rr < 4; ++rr)
      pend[rr] = *(const f32x4*)&twbuf[w][lg * 4 + rr][lr * 4];
  };

  loadK(kA, 0);
  vdma(0, 0);
  {
    int kt = 0;
    while (true) {
      __syncthreads();  // drains DMA+prefetch+prev stores (all ~1 tile old)
      if (kt < qt) { vdma(kt + 1, (kt + 1) & 1); loadK(kB, kt + 1); }
      if (kt > 0) flushA(kt - 1);
      p2body(kA, kt);
      if (++kt > qt) break;
      __syncthreads();
      if (kt < qt) { vdma(kt + 1, (kt + 1) & 1); loadK(kA, kt + 1); }
      flushA(kt - 1);
      p2body(kB, kt);
      if (++kt > qt) break;
    }
  }
  flushA(qt);  // final tile's stores

  // ---------------- zero-fill strictly-upper region ----------------
  const int zstart = (qt + 1) * 64;
  if (zstart < S) {
    const int n4 = (S - zstart) >> 2;
    const f32x4 z = (f32x4){0.f, 0.f, 0.f, 0.f};
    for (int r = 0; r < 64; ++r) {
      float* dst = attn_h + (size_t)(qbase + r) * S + zstart;
      for (int i = t; i < n4; i += 256) *(f32x4*)(dst + i * 4) = z;
    }
  }

  // ---------------- ctx write: [B*S][1024] bf16, granule-swizzled ----------
#pragma unroll
  for (int hc = 0; hc < 4; ++hc)
#pragma unroll
    for (int i = 0; i < 4; ++i) {
      int mr = b * S + qbase + w * 16 + lg * 4 + i;
      int nh = hd * 64 + hc * 16 + lr;
      int kg = nh >> 3, el = nh & 7;
      int kgp = (kg & ~7) | ((kg ^ mr) & 7);
      ctx[(size_t)mr * 1024 + kgp * 8 + el] = f2bf(accpv[hc][i]);
    }
}

// ---------------------------------------------------------------------------
extern "C" void kernel_launch(void* const* d_in, const int* in_sizes, int n_in,
                              void* d_out, int out_size, void* d_ws, size_t ws_size,
                              hipStream_t stream) {
  (void)in_sizes; (void)n_in; (void)out_size; (void)ws_size;
  const float* v_in = (const float*)d_in[0];
  const float* k_in = (const float*)d_in[1];
  const float* q_in = (const float*)d_in[2];
  const float* Wq = (const float*)d_in[4];
  const float* Wk = (const float*)d_in[5];
  const float* Wv = (const float*)d_in[6];
  const float* Wo = (const float*)d_in[7];

  float* out = (float*)d_out;
  float* attn = out + (size_t)2 * 2048 * 1024;

  unsigned short* ws = (unsigned short*)d_ws;
  const size_t MK = (size_t)4096 * 1024;
  const size_t WK = (size_t)1024 * 1024;
  unsigned short* qbfA = ws;
  unsigned short* kbfA = ws + MK;
  unsigned short* vbfA = ws + 2 * MK;
  unsigned short* WqT = ws + 3 * MK;
  unsigned short* WkT = WqT + WK;
  unsigned short* WvT = WkT + WK;
  unsigned short* WoT = WvT + WK;
  unsigned short* q_ws = WoT + WK;   // Q fragment-order tiles
  unsigned short* k_ws = q_ws + MK;  // K fragment-order tiles
  unsigned short* v_ws = k_ws + MK;  // V tiled layout
  unsigned short* ctx_ws = v_ws + MK;

  convin_k<<<dim3(2048, 3), 256, 0, stream>>>(q_in, k_in, v_in, qbfA, kbfA, vbfA);
  convw_k<<<dim3(256, 4), 256, 0, stream>>>(Wq, Wk, Wv, Wo, WqT, WkT, WvT, WoT);

  qkv_gemm<<<dim3(8, 32, 3), 256, 0, stream>>>(qbfA, kbfA, vbfA, WqT, WkT, WvT,
                                               q_ws, k_ws, v_ws);
  attn_k<<<1024, 256, 0, stream>>>(q_ws, k_ws, v_ws, attn, ctx_ws);
  gemmWo<<<dim3(16, 32), 256, 0, stream>>>(ctx_ws, WoT, out);
}

// Round 11
// 212.749 us; speedup vs baseline: 1.1602x; 1.1602x over previous
//
#include <hip/hip_runtime.h>
#include <hip/hip_bf16.h>
#include <cstdint>

// MHA with full attn-matrix output.  B=2 S=2048 D=1024 N=16 H=64.
// d_out = [out (B,S,D) fp32 | attn (B,N,S,S) fp32]

typedef __attribute__((ext_vector_type(4))) float f32x4;
typedef __attribute__((ext_vector_type(8))) short s16x8;
typedef __attribute__((ext_vector_type(8))) unsigned short us8;
typedef __attribute__((ext_vector_type(4))) unsigned short us4;

#define MFMA16(a, b, c) __builtin_amdgcn_mfma_f32_16x16x32_bf16((a), (b), (c), 0, 0, 0)
constexpr float L2E = 1.4426950408889634f;

__device__ __forceinline__ unsigned short f2bf(float f) {
  unsigned int u = __builtin_bit_cast(unsigned int, f);
  u += 0x7FFFu + ((u >> 16) & 1u);  // RNE
  return (unsigned short)(u >> 16);
}
__device__ __forceinline__ unsigned int cvtpk(float lo, float hi) {
  unsigned int r;
  asm("v_cvt_pk_bf16_f32 %0, %1, %2" : "=v"(r) : "v"(lo), "v"(hi));
  return r;
}
__device__ __forceinline__ s16x8 ldfrag(const unsigned short* p) {
  return __builtin_bit_cast(s16x8, *(const us8*)p);
}
// lds dest MUST be wave-uniform; per-lane part goes in g.
__device__ __forceinline__ void gload16(const void* g, void* l) {
  auto* gp = reinterpret_cast<const __attribute__((address_space(1))) unsigned int*>(
      reinterpret_cast<uintptr_t>(g));
  auto* lp = reinterpret_cast<__attribute__((address_space(3))) unsigned int*>(
      reinterpret_cast<uintptr_t>(l));
  __builtin_amdgcn_global_load_lds(gp, lp, 16, 0, 0);
}

// ---------------------------------------------------------------------------
// convert fp32 [4096][1024] -> bf16, granule-swizzled: kg' = (kg&~7)|((kg^m)&7)
// ---------------------------------------------------------------------------
__global__ __launch_bounds__(256) void convin_k(const float* __restrict__ s0,
                                                const float* __restrict__ s1,
                                                const float* __restrict__ s2,
                                                unsigned short* __restrict__ d0,
                                                unsigned short* __restrict__ d1,
                                                unsigned short* __restrict__ d2) {
  const float* s = blockIdx.y == 0 ? s0 : (blockIdx.y == 1 ? s1 : s2);
  unsigned short* d = blockIdx.y == 0 ? d0 : (blockIdx.y == 1 ? d1 : d2);
  int gid = blockIdx.x * 256 + threadIdx.x;
  int m = gid >> 7, kg = gid & 127;
  f32x4 a = *(const f32x4*)(s + (size_t)m * 1024 + kg * 8);
  f32x4 b = *(const f32x4*)(s + (size_t)m * 1024 + kg * 8 + 4);
  us8 o;
#pragma unroll
  for (int j = 0; j < 4; ++j) { o[j] = f2bf(a[j]); o[j + 4] = f2bf(b[j]); }
  int kgp = (kg & ~7) | ((kg ^ m) & 7);
  *(us8*)(d + (size_t)m * 1024 + kgp * 8) = o;
}

// ---------------------------------------------------------------------------
// transpose+convert weights: [1024][1024] f32 -> [c][r] bf16, swizzled.
// ---------------------------------------------------------------------------
__global__ __launch_bounds__(256) void convw_k(const float* __restrict__ w0,
                                               const float* __restrict__ w1,
                                               const float* __restrict__ w2,
                                               const float* __restrict__ w3,
                                               unsigned short* __restrict__ o0,
                                               unsigned short* __restrict__ o1,
                                               unsigned short* __restrict__ o2,
                                               unsigned short* __restrict__ o3) {
  const float* W = blockIdx.y == 0 ? w0 : (blockIdx.y == 1 ? w1 : (blockIdx.y == 2 ? w2 : w3));
  unsigned short* O = blockIdx.y == 0 ? o0 : (blockIdx.y == 1 ? o1 : (blockIdx.y == 2 ? o2 : o3));
  const int t = threadIdx.x;
  const int r0 = (blockIdx.x & 15) * 64, c0 = (blockIdx.x >> 4) * 64;
  __shared__ float tile[64][65];
  {
    int r = t >> 2, cq = (t & 3) * 16;
#pragma unroll
    for (int j = 0; j < 4; ++j) {
      f32x4 v = *(const f32x4*)(W + (size_t)(r0 + r) * 1024 + c0 + cq + j * 4);
#pragma unroll
      for (int e = 0; e < 4; ++e) tile[r][cq + j * 4 + e] = v[e];
    }
  }
  __syncthreads();
  int orow = t >> 2;
  int gr = c0 + orow;
#pragma unroll
  for (int gi = 0; gi < 2; ++gi) {
    int dl = (t & 3) * 16 + gi * 8;
    us8 o;
#pragma unroll
    for (int j = 0; j < 8; ++j) o[j] = f2bf(tile[dl + j][orow]);
    int kg = (r0 + dl) >> 3;
    int kgp = (kg & ~7) | ((kg ^ gr) & 7);
    *(us8*)(O + (size_t)gr * 1024 + kgp * 8) = o;
  }
}

// ---------------------------------------------------------------------------
// Fused QKV projection GEMM: z in {0,1,2} selects (A, W, dst).
// z==0: Q -> MFMA-fragment order (scaled 1/8), same mapping as K.
// z==1: K -> MFMA-fragment order: per head, per 64-row tile:
//        off = fc*1024 + half*512 + lane*8 + j   where fc=(s>>4)&3,
//        half=h>>5, lane=((h>>3)&3)*16 + (s&15), j=h&7.
// z==2: V -> per-64-tile layout [h][g^(h&7)][s&7] (DMA-stageable, proven).
// ---------------------------------------------------------------------------
__global__ __launch_bounds__(256) void qkv_gemm(
    const unsigned short* __restrict__ Aq, const unsigned short* __restrict__ Ak,
    const unsigned short* __restrict__ Av, const unsigned short* __restrict__ Bq,
    const unsigned short* __restrict__ Bk, const unsigned short* __restrict__ Bv,
    unsigned short* __restrict__ Oq, unsigned short* __restrict__ Ok,
    unsigned short* __restrict__ Ov) {
  const int z = blockIdx.z;
  const unsigned short* A = z == 0 ? Aq : (z == 1 ? Ak : Av);
  const unsigned short* Bt = z == 0 ? Bq : (z == 1 ? Bk : Bv);

  __shared__ __align__(16) unsigned short lds[16384];
  const int t = threadIdx.x, w = t >> 6, lane = t & 63;
  const int lr = lane & 15, lg = lane >> 4;
  const int wr = (w >> 1) * 64, wc = (w & 1) * 64;
  const int m0 = blockIdx.y * 128, n0 = blockIdx.x * 128;
  const int srow = w * 32 + (lane >> 3), sg = lane & 7;

  f32x4 acc[4][4];
#pragma unroll
  for (int i = 0; i < 4; ++i)
#pragma unroll
    for (int j = 0; j < 4; ++j) acc[i][j] = (f32x4){0.f, 0.f, 0.f, 0.f};

  for (int k0 = 0; k0 < 1024; k0 += 64) {
#pragma unroll
    for (int q = 0; q < 4; ++q)
      gload16(A + (size_t)(m0 + srow + q * 8) * 1024 + k0 + sg * 8,
              &lds[(w * 32 + q * 8) * 64]);
#pragma unroll
    for (int q = 0; q < 4; ++q)
      gload16(Bt + (size_t)(n0 + srow + q * 8) * 1024 + k0 + sg * 8,
              &lds[8192 + (w * 32 + q * 8) * 64]);
    __syncthreads();
#pragma unroll
    for (int r2 = 0; r2 < 2; ++r2) {
      const int koff = ((r2 * 4 + lg) ^ (lr & 7)) * 8;
      s16x8 af[4], bfr[4];
#pragma unroll
      for (int x = 0; x < 4; ++x) af[x] = ldfrag(&lds[(wr + x * 16 + lr) * 64 + koff]);
#pragma unroll
      for (int x = 0; x < 4; ++x) bfr[x] = ldfrag(&lds[8192 + (wc + x * 16 + lr) * 64 + koff]);
#pragma unroll
      for (int am = 0; am < 4; ++am)
#pragma unroll
        for (int bn = 0; bn < 4; ++bn) acc[am][bn] = MFMA16(af[am], bfr[bn], acc[am][bn]);
    }
    __syncthreads();
  }

  if (z < 2) {
    unsigned short* C = z == 0 ? Oq : Ok;
    const float scale = z == 0 ? 0.125f : 1.0f;
#pragma unroll
    for (int am = 0; am < 4; ++am)
#pragma unroll
      for (int bn = 0; bn < 4; ++bn)
#pragma unroll
        for (int i = 0; i < 4; ++i) {
          int gr = m0 + wr + am * 16 + lg * 4 + i;  // b*S + s
          int gc = n0 + wc + bn * 16 + lr;          // n*H + h
          int bb = gr >> 11, ss = gr & 2047;
          int nn = gc >> 6, hh = gc & 63;
          size_t base = ((size_t)(bb * 16 + nn)) * 131072 + (size_t)(ss >> 6) * 4096;
          int off = ((ss >> 4) & 3) * 1024 + (hh >> 5) * 512 +
                    (((hh >> 3) & 3) * 16 + (ss & 15)) * 8 + (hh & 7);
          C[base + off] = f2bf(acc[am][bn][i] * scale);
        }
  } else {
#pragma unroll
    for (int am = 0; am < 4; ++am)
#pragma unroll
      for (int bn = 0; bn < 4; ++bn)
#pragma unroll
        for (int i = 0; i < 4; ++i) {
          int gr = m0 + wr + am * 16 + lg * 4 + i;
          int gc = n0 + wc + bn * 16 + lr;
          int bb = gr >> 11, ss = gr & 2047;
          int nn = gc >> 6, hh = gc & 63;
          size_t base = ((size_t)(bb * 16 + nn)) * 131072 + (size_t)(ss >> 6) * 4096;
          int off = hh * 64 + (((((ss >> 3) & 7) ^ (hh & 7))) << 3) + (ss & 7);
          Ov[base + off] = f2bf(acc[am][bn][i]);
        }
  }
}

// ---------------------------------------------------------------------------
// Wo GEMM: out[4096,1024] fp32 = ctx(bf16 swz) * WoT.  128x64 tile -> 512 blk.
// ---------------------------------------------------------------------------
__global__ __launch_bounds__(256) void gemmWo(const unsigned short* __restrict__ A,
                                              const unsigned short* __restrict__ Bt,
                                              float* __restrict__ C) {
  __shared__ __align__(16) unsigned short lds[12288];
  const int t = threadIdx.x, w = t >> 6, lane = t & 63;
  const int lr = lane & 15, lg = lane >> 4;
  const int wr = (w >> 1) * 64, wc = (w & 1) * 32;
  const int m0 = blockIdx.y * 128, n0 = blockIdx.x * 64;

  f32x4 acc[4][2];
#pragma unroll
  for (int i = 0; i < 4; ++i)
#pragma unroll
    for (int j = 0; j < 2; ++j) acc[i][j] = (f32x4){0.f, 0.f, 0.f, 0.f};

  for (int k0 = 0; k0 < 1024; k0 += 64) {
#pragma unroll
    for (int q = 0; q < 4; ++q)
      gload16(A + (size_t)(m0 + w * 32 + q * 8 + (lane >> 3)) * 1024 + k0 + (lane & 7) * 8,
              &lds[(w * 32 + q * 8) * 64]);
#pragma unroll
    for (int q = 0; q < 2; ++q)
      gload16(Bt + (size_t)(n0 + w * 16 + q * 8 + (lane >> 3)) * 1024 + k0 + (lane & 7) * 8,
              &lds[8192 + (w * 16 + q * 8) * 64]);
    __syncthreads();
#pragma unroll
    for (int r2 = 0; r2 < 2; ++r2) {
      const int koff = ((r2 * 4 + lg) ^ (lr & 7)) * 8;
      s16x8 af[4], bfr[2];
#pragma unroll
      for (int x = 0; x < 4; ++x) af[x] = ldfrag(&lds[(wr + x * 16 + lr) * 64 + koff]);
#pragma unroll
      for (int x = 0; x < 2; ++x) bfr[x] = ldfrag(&lds[8192 + (wc + x * 16 + lr) * 64 + koff]);
#pragma unroll
      for (int am = 0; am < 4; ++am)
#pragma unroll
        for (int bn = 0; bn < 2; ++bn) acc[am][bn] = MFMA16(af[am], bfr[bn], acc[am][bn]);
    }
    __syncthreads();
  }
#pragma unroll
  for (int am = 0; am < 4; ++am)
#pragma unroll
    for (int bn = 0; bn < 2; ++bn)
#pragma unroll
      for (int i = 0; i < 4; ++i) {
        int gr = m0 + wr + am * 16 + lg * 4 + i;
        int gc = n0 + wc + bn * 16 + lr;
        C[(size_t)gr * 1024 + gc] = acc[am][bn][i];
      }
}

// ---------------------------------------------------------------------------
// Fused causal attention, swapped-QK.  Block=(b,head,64 q-rows), 4 waves.
// Q/K in fragment-order global layout (lane-contiguous 1KB bursts, no LDS).
// K software-pipelined into registers (2-state kA/kB).  Max-free softmax.
// V DMA-staged double-buffered.  qt DESCENDING dispatch (LPT load balance).
// attn + zero-fill stores NONTEMPORAL (keep K/V/ctx L2-resident).
// ---------------------------------------------------------------------------
__global__ __launch_bounds__(256) void attn_k(const unsigned short* __restrict__ qw,
                                              const unsigned short* __restrict__ kw,
                                              const unsigned short* __restrict__ vw,
                                              float* __restrict__ attn,
                                              unsigned short* __restrict__ ctx) {
  constexpr int S = 2048, N = 16;
  const int flat = blockIdx.x;
  const int nf = (flat & 7) * 128 + (flat >> 3);  // XCD-chunked
  const int qt = 31 - (nf & 31);                  // heaviest blocks first
  const int hd = (nf >> 5) & 15, b = nf >> 9;
  const int qbase = qt * 64;
  const int t = threadIdx.x, w = t >> 6, lane = t & 63;
  const int lr = lane & 15, lg = lane >> 4;
  const size_t headoff = ((size_t)(b * N + hd)) * S * 64;
  const unsigned short* qh = qw + headoff;  // fragment-order tiles
  const unsigned short* kh = kw + headoff;  // fragment-order tiles
  const unsigned short* vh = vw + headoff;  // tiled V
  float* attn_h = attn + ((size_t)(b * N + hd)) * S * S;
  const int qrow = qbase + w * 16 + lr;

  __shared__ __align__(16) unsigned short ldsv[2][4096];
  __shared__ __align__(16) float twbuf[4][16][72];

  s16x8 qf0 = ldfrag(qh + (size_t)qt * 4096 + w * 1024 + lane * 8);
  s16x8 qf1 = ldfrag(qh + (size_t)qt * 4096 + w * 1024 + 512 + lane * 8);

  s16x8 kA[8], kB[8];
  auto loadK = [&](s16x8(&kf)[8], int kt) {
    const unsigned short* kb = kh + (size_t)kt * 4096;
#pragma unroll
    for (int fc = 0; fc < 4; ++fc) {
      kf[fc * 2] = ldfrag(kb + fc * 1024 + lane * 8);
      kf[fc * 2 + 1] = ldfrag(kb + fc * 1024 + 512 + lane * 8);
    }
  };

  // ---------------- pass 1: per-row sum of exp (max-free, pipelined) -------
  float lsum = 0.f;
  auto p1body = [&](s16x8(&kf)[8], int kt) {
    float ts = 0.f;
#pragma unroll
    for (int fc = 0; fc < 4; ++fc) {
      f32x4 a = (f32x4){0.f, 0.f, 0.f, 0.f};
      a = MFMA16(kf[fc * 2], qf0, a);
      a = MFMA16(kf[fc * 2 + 1], qf1, a);
      if (kt == qt) {
#pragma unroll
        for (int i = 0; i < 4; ++i)
          if (qbase + fc * 16 + lg * 4 + i > qrow) a[i] = -3.0e38f;
      }
#pragma unroll
      for (int i = 0; i < 4; ++i) ts += __builtin_amdgcn_exp2f(a[i] * L2E);
    }
    lsum += ts;
  };
  loadK(kA, 0);
  {
    int kt = 0;
    while (true) {
      if (kt < qt) loadK(kB, kt + 1);
      p1body(kA, kt);
      if (++kt > qt) break;
      if (kt < qt) loadK(kA, kt + 1);
      p1body(kB, kt);
      if (++kt > qt) break;
    }
  }
  lsum += __shfl_xor(lsum, 16);
  lsum += __shfl_xor(lsum, 32);
  const float c0 = -__builtin_amdgcn_logf(lsum);  // v_log_f32=log2; p=exp2(s*L2E+c0)

  // ---------------- pass 2: attn write + PV (pipelined) ----------------
  f32x4 accpv[4];
#pragma unroll
  for (int i = 0; i < 4; ++i) accpv[i] = (f32x4){0.f, 0.f, 0.f, 0.f};
  const int src0 = lr + 32 * (lg & 1), src1 = src0 + 16;
  const bool hiFc = (lg >> 1) & 1;

  auto vdma = [&](int kt, int buf) {
    const unsigned short* vsrc = vh + (size_t)kt * 4096;
    gload16(vsrc + (w * 128 + lane) * 8, &ldsv[buf][w * 1024]);
    gload16(vsrc + (w * 128 + 64 + lane) * 8, &ldsv[buf][w * 1024 + 512]);
  };

  auto p2body = [&](s16x8(&kf)[8], int kt) {
    const int cb = kt & 1;
    f32x4 s[4];
#pragma unroll
    for (int fc = 0; fc < 4; ++fc) {
      f32x4 a = (f32x4){0.f, 0.f, 0.f, 0.f};
      a = MFMA16(kf[fc * 2], qf0, a);
      a = MFMA16(kf[fc * 2 + 1], qf1, a);
      s[fc] = a;
    }
    unsigned int Wlo[4], Whi[4];
#pragma unroll
    for (int fc = 0; fc < 4; ++fc) {
      f32x4 p;
#pragma unroll
      for (int i = 0; i < 4; ++i)
        p[i] = __builtin_amdgcn_exp2f(__builtin_fmaf(s[fc][i], L2E, c0));
      if (kt == qt) {
#pragma unroll
        for (int i = 0; i < 4; ++i)
          if (qbase + fc * 16 + lg * 4 + i > qrow) p[i] = 0.0f;
      }
      *(f32x4*)&twbuf[w][lr][fc * 16 + lg * 4] = p;
      Wlo[fc] = cvtpk(p[0], p[1]);
      Whi[fc] = cvtpk(p[2], p[3]);
    }
#pragma unroll
    for (int ks = 0; ks < 2; ++ks) {
      unsigned int d0a = __shfl((int)Wlo[2 * ks], src0, 64);
      unsigned int d0b = __shfl((int)Wlo[2 * ks + 1], src0, 64);
      unsigned int d1a = __shfl((int)Whi[2 * ks], src0, 64);
      unsigned int d1b = __shfl((int)Whi[2 * ks + 1], src0, 64);
      unsigned int d2a = __shfl((int)Wlo[2 * ks], src1, 64);
      unsigned int d2b = __shfl((int)Wlo[2 * ks + 1], src1, 64);
      unsigned int d3a = __shfl((int)Whi[2 * ks], src1, 64);
      unsigned int d3b = __shfl((int)Whi[2 * ks + 1], src1, 64);
      unsigned int pd[4] = {hiFc ? d0b : d0a, hiFc ? d1b : d1a,
                            hiFc ? d2b : d2a, hiFc ? d3b : d3a};
      s16x8 pa = __builtin_bit_cast(s16x8, *(us8*)pd);
#pragma unroll
      for (int hc = 0; hc < 4; ++hc) {
        s16x8 vb = ldfrag(&ldsv[cb][(hc * 16 + lr) * 64 + (((ks * 4 + lg) ^ (lr & 7)) << 3)]);
        accpv[hc] = MFMA16(pa, vb, accpv[hc]);
      }
    }
    // coalesced transposed attn store, nontemporal (never re-read on device)
#pragma unroll
    for (int rr = 0; rr < 4; ++rr) {
      f32x4 v = *(const f32x4*)&twbuf[w][lg * 4 + rr][lr * 4];
      __builtin_nontemporal_store(
          v, (f32x4*)(attn_h + (size_t)(qbase + w * 16 + lg * 4 + rr) * S + kt * 64 + lr * 4));
    }
  };

  loadK(kA, 0);
  vdma(0, 0);
  {
    int kt = 0;
    while (true) {
      __syncthreads();  // drains DMA+prefetch: V(kt)+K(kt) ready; V buf kt^1 free
      if (kt < qt) { vdma(kt + 1, (kt + 1) & 1); loadK(kB, kt + 1); }
      p2body(kA, kt);
      if (++kt > qt) break;
      __syncthreads();
      if (kt < qt) { vdma(kt + 1, (kt + 1) & 1); loadK(kA, kt + 1); }
      p2body(kB, kt);
      if (++kt > qt) break;
    }
  }

  // ---------------- zero-fill strictly-upper region (nontemporal) ----------
  const int zstart = (qt + 1) * 64;
  if (zstart < S) {
    const int n4 = (S - zstart) >> 2;
    const f32x4 z = (f32x4){0.f, 0.f, 0.f, 0.f};
    for (int r = 0; r < 64; ++r) {
      float* dst = attn_h + (size_t)(qbase + r) * S + zstart;
      for (int i = t; i < n4; i += 256)
        __builtin_nontemporal_store(z, (f32x4*)(dst + i * 4));
    }
  }

  // ---------------- ctx write: [B*S][1024] bf16, granule-swizzled ----------
#pragma unroll
  for (int hc = 0; hc < 4; ++hc)
#pragma unroll
    for (int i = 0; i < 4; ++i) {
      int mr = b * S + qbase + w * 16 + lg * 4 + i;
      int nh = hd * 64 + hc * 16 + lr;
      int kg = nh >> 3, el = nh & 7;
      int kgp = (kg & ~7) | ((kg ^ mr) & 7);
      ctx[(size_t)mr * 1024 + kgp * 8 + el] = f2bf(accpv[hc][i]);
    }
}

// ---------------------------------------------------------------------------
extern "C" void kernel_launch(void* const* d_in, const int* in_sizes, int n_in,
                              void* d_out, int out_size, void* d_ws, size_t ws_size,
                              hipStream_t stream) {
  (void)in_sizes; (void)n_in; (void)out_size; (void)ws_size;
  const float* v_in = (const float*)d_in[0];
  const float* k_in = (const float*)d_in[1];
  const float* q_in = (const float*)d_in[2];
  const float* Wq = (const float*)d_in[4];
  const float* Wk = (const float*)d_in[5];
  const float* Wv = (const float*)d_in[6];
  const float* Wo = (const float*)d_in[7];

  float* out = (float*)d_out;
  float* attn = out + (size_t)2 * 2048 * 1024;

  unsigned short* ws = (unsigned short*)d_ws;
  const size_t MK = (size_t)4096 * 1024;
  const size_t WK = (size_t)1024 * 1024;
  unsigned short* qbfA = ws;
  unsigned short* kbfA = ws + MK;
  unsigned short* vbfA = ws + 2 * MK;
  unsigned short* WqT = ws + 3 * MK;
  unsigned short* WkT = WqT + WK;
  unsigned short* WvT = WkT + WK;
  unsigned short* WoT = WvT + WK;
  unsigned short* q_ws = WoT + WK;   // Q fragment-order tiles
  unsigned short* k_ws = q_ws + MK;  // K fragment-order tiles
  unsigned short* v_ws = k_ws + MK;  // V tiled layout
  unsigned short* ctx_ws = v_ws + MK;

  convin_k<<<dim3(2048, 3), 256, 0, stream>>>(q_in, k_in, v_in, qbfA, kbfA, vbfA);
  convw_k<<<dim3(256, 4), 256, 0, stream>>>(Wq, Wk, Wv, Wo, WqT, WkT, WvT, WoT);

  qkv_gemm<<<dim3(8, 32, 3), 256, 0, stream>>>(qbfA, kbfA, vbfA, WqT, WkT, WvT,
                                               q_ws, k_ws, v_ws);
  attn_k<<<1024, 256, 0, stream>>>(q_ws, k_ws, v_ws, attn, ctx_ws);
  gemmWo<<<dim3(16, 32), 256, 0, stream>>>(ctx_ws, WoT, out);
}

// Round 12
// 208.076 us; speedup vs baseline: 1.1862x; 1.0225x over previous
//
#include <hip/hip_runtime.h>
#include <hip/hip_bf16.h>
#include <cstdint>

// MHA with full attn-matrix output.  B=2 S=2048 D=1024 N=16 H=64.
// d_out = [out (B,S,D) fp32 | attn (B,N,S,S) fp32]

typedef __attribute__((ext_vector_type(4))) float f32x4;
typedef __attribute__((ext_vector_type(8))) short s16x8;
typedef __attribute__((ext_vector_type(8))) unsigned short us8;
typedef __attribute__((ext_vector_type(4))) unsigned short us4;

#define MFMA16(a, b, c) __builtin_amdgcn_mfma_f32_16x16x32_bf16((a), (b), (c), 0, 0, 0)
constexpr float L2E = 1.4426950408889634f;

__device__ __forceinline__ unsigned short f2bf(float f) {
  unsigned int u = __builtin_bit_cast(unsigned int, f);
  u += 0x7FFFu + ((u >> 16) & 1u);  // RNE
  return (unsigned short)(u >> 16);
}
__device__ __forceinline__ unsigned int cvtpk(float lo, float hi) {
  unsigned int r;
  asm("v_cvt_pk_bf16_f32 %0, %1, %2" : "=v"(r) : "v"(lo), "v"(hi));
  return r;
}
__device__ __forceinline__ s16x8 ldfrag(const unsigned short* p) {
  return __builtin_bit_cast(s16x8, *(const us8*)p);
}
// lds dest MUST be wave-uniform; per-lane part goes in g.
__device__ __forceinline__ void gload16(const void* g, void* l) {
  auto* gp = reinterpret_cast<const __attribute__((address_space(1))) unsigned int*>(
      reinterpret_cast<uintptr_t>(g));
  auto* lp = reinterpret_cast<__attribute__((address_space(3))) unsigned int*>(
      reinterpret_cast<uintptr_t>(l));
  __builtin_amdgcn_global_load_lds(gp, lp, 16, 0, 0);
}

// ---------------------------------------------------------------------------
// Merged conversion kernel.  Blocks [0,6144): inputs fp32->bf16 granule-swz.
// Blocks [6144,7168): weights transpose+convert+swz.
// ---------------------------------------------------------------------------
__global__ __launch_bounds__(256) void conv_k(
    const float* __restrict__ s0, const float* __restrict__ s1,
    const float* __restrict__ s2, unsigned short* __restrict__ d0,
    unsigned short* __restrict__ d1, unsigned short* __restrict__ d2,
    const float* __restrict__ w0, const float* __restrict__ w1,
    const float* __restrict__ w2, const float* __restrict__ w3,
    unsigned short* __restrict__ o0, unsigned short* __restrict__ o1,
    unsigned short* __restrict__ o2, unsigned short* __restrict__ o3) {
  const int blk = blockIdx.x;
  const int t = threadIdx.x;
  __shared__ float tile[64][65];
  if (blk < 6144) {
    const int y = blk >> 11, x = blk & 2047;
    const float* s = y == 0 ? s0 : (y == 1 ? s1 : s2);
    unsigned short* d = y == 0 ? d0 : (y == 1 ? d1 : d2);
    int gid = x * 256 + t;
    int m = gid >> 7, kg = gid & 127;
    f32x4 a = *(const f32x4*)(s + (size_t)m * 1024 + kg * 8);
    f32x4 b = *(const f32x4*)(s + (size_t)m * 1024 + kg * 8 + 4);
    us8 o;
#pragma unroll
    for (int j = 0; j < 4; ++j) { o[j] = f2bf(a[j]); o[j + 4] = f2bf(b[j]); }
    int kgp = (kg & ~7) | ((kg ^ m) & 7);
    *(us8*)(d + (size_t)m * 1024 + kgp * 8) = o;
  } else {
    const int r = blk - 6144;
    const int y = r >> 8, x = r & 255;
    const float* W = y == 0 ? w0 : (y == 1 ? w1 : (y == 2 ? w2 : w3));
    unsigned short* O = y == 0 ? o0 : (y == 1 ? o1 : (y == 2 ? o2 : o3));
    const int r0 = (x & 15) * 64, c0 = (x >> 4) * 64;
    {
      int rr = t >> 2, cq = (t & 3) * 16;
#pragma unroll
      for (int j = 0; j < 4; ++j) {
        f32x4 v = *(const f32x4*)(W + (size_t)(r0 + rr) * 1024 + c0 + cq + j * 4);
#pragma unroll
        for (int e = 0; e < 4; ++e) tile[rr][cq + j * 4 + e] = v[e];
      }
    }
    __syncthreads();
    int orow = t >> 2;
    int gr = c0 + orow;
#pragma unroll
    for (int gi = 0; gi < 2; ++gi) {
      int dl = (t & 3) * 16 + gi * 8;
      us8 o;
#pragma unroll
      for (int j = 0; j < 8; ++j) o[j] = f2bf(tile[dl + j][orow]);
      int kg = (r0 + dl) >> 3;
      int kgp = (kg & ~7) | ((kg ^ gr) & 7);
      *(us8*)(O + (size_t)gr * 1024 + kgp * 8) = o;
    }
  }
}

// ---------------------------------------------------------------------------
// Fused QKV projection GEMM, XCD-chunked dispatch, LDS-transpose epilogue.
// z==0: Q -> MFMA-fragment order (scaled 1/8).   z==1: K -> fragment order.
// z==2: V -> per-64-tile layout [h][g^(h&7)][s&7].
// Block output = 4 contiguous 8KB sub-tiles -> scatter to LDS, stream 16B.
// ---------------------------------------------------------------------------
__global__ __launch_bounds__(256) void qkv_gemm(
    const unsigned short* __restrict__ Aq, const unsigned short* __restrict__ Ak,
    const unsigned short* __restrict__ Av, const unsigned short* __restrict__ Bq,
    const unsigned short* __restrict__ Bk, const unsigned short* __restrict__ Bv,
    unsigned short* __restrict__ Oq, unsigned short* __restrict__ Ok,
    unsigned short* __restrict__ Ov) {
  const int z = blockIdx.z;
  const unsigned short* A = z == 0 ? Aq : (z == 1 ? Ak : Av);
  const unsigned short* Bt = z == 0 ? Bq : (z == 1 ? Bk : Bv);

  __shared__ __align__(16) unsigned short lds[16384];
  const int t = threadIdx.x, w = t >> 6, lane = t & 63;
  const int lr = lane & 15, lg = lane >> 4;
  const int wr = (w >> 1) * 64, wc = (w & 1) * 64;
  const int xf = blockIdx.x;                    // 256 blocks, XCD-chunked
  const int nfb = (xf & 7) * 32 + (xf >> 3);    // each XCD: 4 A-rows x 8 B-cols
  const int m0 = (nfb >> 3) * 128, n0 = (nfb & 7) * 128;
  const int srow = w * 32 + (lane >> 3), sg = lane & 7;

  f32x4 acc[4][4];
#pragma unroll
  for (int i = 0; i < 4; ++i)
#pragma unroll
    for (int j = 0; j < 4; ++j) acc[i][j] = (f32x4){0.f, 0.f, 0.f, 0.f};

  for (int k0 = 0; k0 < 1024; k0 += 64) {
#pragma unroll
    for (int q = 0; q < 4; ++q)
      gload16(A + (size_t)(m0 + srow + q * 8) * 1024 + k0 + sg * 8,
              &lds[(w * 32 + q * 8) * 64]);
#pragma unroll
    for (int q = 0; q < 4; ++q)
      gload16(Bt + (size_t)(n0 + srow + q * 8) * 1024 + k0 + sg * 8,
              &lds[8192 + (w * 32 + q * 8) * 64]);
    __syncthreads();
#pragma unroll
    for (int r2 = 0; r2 < 2; ++r2) {
      const int koff = ((r2 * 4 + lg) ^ (lr & 7)) * 8;
      s16x8 af[4], bfr[4];
#pragma unroll
      for (int x = 0; x < 4; ++x) af[x] = ldfrag(&lds[(wr + x * 16 + lr) * 64 + koff]);
#pragma unroll
      for (int x = 0; x < 4; ++x) bfr[x] = ldfrag(&lds[8192 + (wc + x * 16 + lr) * 64 + koff]);
#pragma unroll
      for (int am = 0; am < 4; ++am)
#pragma unroll
        for (int bn = 0; bn < 4; ++bn) acc[am][bn] = MFMA16(af[am], bfr[bn], acc[am][bn]);
    }
    __syncthreads();
  }

  // ---- epilogue: scatter to LDS (4 x 4096-u16 sub-tiles), stream out ----
  const float scale = z == 0 ? 0.125f : 1.0f;
#pragma unroll
  for (int am = 0; am < 4; ++am)
#pragma unroll
    for (int bn = 0; bn < 4; ++bn)
#pragma unroll
      for (int i = 0; i < 4; ++i) {
        int grl = wr + am * 16 + lg * 4 + i;  // local row 0..127  (= ss low bits)
        int gcl = wc + bn * 16 + lr;          // local col 0..127  (= hh low bits)
        int st = grl >> 6, s6 = grl & 63;
        int hd2 = gcl >> 6, h6 = gcl & 63;
        int off;
        if (z < 2)
          off = ((s6 >> 4) & 3) * 1024 + (h6 >> 5) * 512 +
                (((h6 >> 3) & 3) * 16 + (s6 & 15)) * 8 + (h6 & 7);
        else
          off = h6 * 64 + ((((s6 >> 3) & 7) ^ (h6 & 7)) << 3) + (s6 & 7);
        lds[(st * 2 + hd2) * 4096 + off] = f2bf(acc[am][bn][i] * scale);
      }
  __syncthreads();
  unsigned short* C = z == 0 ? Oq : (z == 1 ? Ok : Ov);
  const int bb = m0 >> 11, t0 = (m0 & 2047) >> 6, nn0 = n0 >> 6;
#pragma unroll
  for (int c = 0; c < 8; ++c) {
    int g = c * 256 + t;  // granule 0..2047 (8 u16 each)
    int sub = g >> 9, inner = g & 511;
    int st = sub >> 1, hd2 = sub & 1;
    size_t dst = ((size_t)(bb * 16 + nn0 + hd2)) * 131072 + (size_t)(t0 + st) * 4096 +
                 (size_t)inner * 8;
    *(us8*)(C + dst) = *(const us8*)&lds[g * 8];
  }
}

// ---------------------------------------------------------------------------
// Wo GEMM: out[4096,1024] fp32 = ctx(bf16 swz) * WoT.  128x64 tile, 512 blk,
// XCD-chunked dispatch, nontemporal out stores.
// ---------------------------------------------------------------------------
__global__ __launch_bounds__(256) void gemmWo(const unsigned short* __restrict__ A,
                                              const unsigned short* __restrict__ Bt,
                                              float* __restrict__ C) {
  __shared__ __align__(16) unsigned short lds[12288];
  const int t = threadIdx.x, w = t >> 6, lane = t & 63;
  const int lr = lane & 15, lg = lane >> 4;
  const int wr = (w >> 1) * 64, wc = (w & 1) * 32;
  const int xf = blockIdx.x;                    // 512 blocks
  const int nfb = (xf & 7) * 64 + (xf >> 3);    // each XCD: 4 A-rows x 16 B-cols
  const int m0 = (nfb >> 4) * 128, n0 = (nfb & 15) * 64;

  f32x4 acc[4][2];
#pragma unroll
  for (int i = 0; i < 4; ++i)
#pragma unroll
    for (int j = 0; j < 2; ++j) acc[i][j] = (f32x4){0.f, 0.f, 0.f, 0.f};

  for (int k0 = 0; k0 < 1024; k0 += 64) {
#pragma unroll
    for (int q = 0; q < 4; ++q)
      gload16(A + (size_t)(m0 + w * 32 + q * 8 + (lane >> 3)) * 1024 + k0 + (lane & 7) * 8,
              &lds[(w * 32 + q * 8) * 64]);
#pragma unroll
    for (int q = 0; q < 2; ++q)
      gload16(Bt + (size_t)(n0 + w * 16 + q * 8 + (lane >> 3)) * 1024 + k0 + (lane & 7) * 8,
              &lds[8192 + (w * 16 + q * 8) * 64]);
    __syncthreads();
#pragma unroll
    for (int r2 = 0; r2 < 2; ++r2) {
      const int koff = ((r2 * 4 + lg) ^ (lr & 7)) * 8;
      s16x8 af[4], bfr[2];
#pragma unroll
      for (int x = 0; x < 4; ++x) af[x] = ldfrag(&lds[(wr + x * 16 + lr) * 64 + koff]);
#pragma unroll
      for (int x = 0; x < 2; ++x) bfr[x] = ldfrag(&lds[8192 + (wc + x * 16 + lr) * 64 + koff]);
#pragma unroll
      for (int am = 0; am < 4; ++am)
#pragma unroll
        for (int bn = 0; bn < 2; ++bn) acc[am][bn] = MFMA16(af[am], bfr[bn], acc[am][bn]);
    }
    __syncthreads();
  }
#pragma unroll
  for (int am = 0; am < 4; ++am)
#pragma unroll
    for (int bn = 0; bn < 2; ++bn)
#pragma unroll
      for (int i = 0; i < 4; ++i) {
        int gr = m0 + wr + am * 16 + lg * 4 + i;
        int gc = n0 + wc + bn * 16 + lr;
        __builtin_nontemporal_store(acc[am][bn][i], &C[(size_t)gr * 1024 + gc]);
      }
}

// ---------------------------------------------------------------------------
// Fused causal attention, swapped-QK.  Block=(b,head,64 q-rows), 4 waves.
// Q/K in fragment-order global layout (lane-contiguous 1KB bursts, no LDS).
// K software-pipelined into registers (2-state kA/kB).  Max-free softmax.
// V DMA-staged double-buffered.  qt DESCENDING dispatch (LPT load balance).
// attn + zero-fill stores NONTEMPORAL (keep K/V/ctx L2-resident).
// ---------------------------------------------------------------------------
__global__ __launch_bounds__(256) void attn_k(const unsigned short* __restrict__ qw,
                                              const unsigned short* __restrict__ kw,
                                              const unsigned short* __restrict__ vw,
                                              float* __restrict__ attn,
                                              unsigned short* __restrict__ ctx) {
  constexpr int S = 2048, N = 16;
  const int flat = blockIdx.x;
  const int nf = (flat & 7) * 128 + (flat >> 3);  // XCD-chunked
  const int qt = 31 - (nf & 31);                  // heaviest blocks first
  const int hd = (nf >> 5) & 15, b = nf >> 9;
  const int qbase = qt * 64;
  const int t = threadIdx.x, w = t >> 6, lane = t & 63;
  const int lr = lane & 15, lg = lane >> 4;
  const size_t headoff = ((size_t)(b * N + hd)) * S * 64;
  const unsigned short* qh = qw + headoff;  // fragment-order tiles
  const unsigned short* kh = kw + headoff;  // fragment-order tiles
  const unsigned short* vh = vw + headoff;  // tiled V
  float* attn_h = attn + ((size_t)(b * N + hd)) * S * S;
  const int qrow = qbase + w * 16 + lr;

  __shared__ __align__(16) unsigned short ldsv[2][4096];
  __shared__ __align__(16) float twbuf[4][16][76];

  s16x8 qf0 = ldfrag(qh + (size_t)qt * 4096 + w * 1024 + lane * 8);
  s16x8 qf1 = ldfrag(qh + (size_t)qt * 4096 + w * 1024 + 512 + lane * 8);

  s16x8 kA[8], kB[8];
  auto loadK = [&](s16x8(&kf)[8], int kt) {
    const unsigned short* kb = kh + (size_t)kt * 4096;
#pragma unroll
    for (int fc = 0; fc < 4; ++fc) {
      kf[fc * 2] = ldfrag(kb + fc * 1024 + lane * 8);
      kf[fc * 2 + 1] = ldfrag(kb + fc * 1024 + 512 + lane * 8);
    }
  };

  // ---------------- pass 1: per-row sum of exp (max-free, pipelined) -------
  float lsum = 0.f;
  auto p1body = [&](s16x8(&kf)[8], int kt) {
    float ts = 0.f;
#pragma unroll
    for (int fc = 0; fc < 4; ++fc) {
      f32x4 a = (f32x4){0.f, 0.f, 0.f, 0.f};
      a = MFMA16(kf[fc * 2], qf0, a);
      a = MFMA16(kf[fc * 2 + 1], qf1, a);
      if (kt == qt) {
#pragma unroll
        for (int i = 0; i < 4; ++i)
          if (qbase + fc * 16 + lg * 4 + i > qrow) a[i] = -3.0e38f;
      }
#pragma unroll
      for (int i = 0; i < 4; ++i) ts += __builtin_amdgcn_exp2f(a[i] * L2E);
    }
    lsum += ts;
  };
  loadK(kA, 0);
  {
    int kt = 0;
    while (true) {
      if (kt < qt) loadK(kB, kt + 1);
      p1body(kA, kt);
      if (++kt > qt) break;
      if (kt < qt) loadK(kA, kt + 1);
      p1body(kB, kt);
      if (++kt > qt) break;
    }
  }
  lsum += __shfl_xor(lsum, 16);
  lsum += __shfl_xor(lsum, 32);
  const float c0 = -__builtin_amdgcn_logf(lsum);  // v_log_f32=log2; p=exp2(s*L2E+c0)

  // ---------------- pass 2: attn write + PV (pipelined) ----------------
  f32x4 accpv[4];
#pragma unroll
  for (int i = 0; i < 4; ++i) accpv[i] = (f32x4){0.f, 0.f, 0.f, 0.f};
  const int src0 = lr + 32 * (lg & 1), src1 = src0 + 16;
  const bool hiFc = (lg >> 1) & 1;

  auto vdma = [&](int kt, int buf) {
    const unsigned short* vsrc = vh + (size_t)kt * 4096;
    gload16(vsrc + (w * 128 + lane) * 8, &ldsv[buf][w * 1024]);
    gload16(vsrc + (w * 128 + 64 + lane) * 8, &ldsv[buf][w * 1024 + 512]);
  };

  auto p2body = [&](s16x8(&kf)[8], int kt) {
    const int cb = kt & 1;
    f32x4 s[4];
#pragma unroll
    for (int fc = 0; fc < 4; ++fc) {
      f32x4 a = (f32x4){0.f, 0.f, 0.f, 0.f};
      a = MFMA16(kf[fc * 2], qf0, a);
      a = MFMA16(kf[fc * 2 + 1], qf1, a);
      s[fc] = a;
    }
    unsigned int Wlo[4], Whi[4];
#pragma unroll
    for (int fc = 0; fc < 4; ++fc) {
      f32x4 p;
#pragma unroll
      for (int i = 0; i < 4; ++i)
        p[i] = __builtin_amdgcn_exp2f(__builtin_fmaf(s[fc][i], L2E, c0));
      if (kt == qt) {
#pragma unroll
        for (int i = 0; i < 4; ++i)
          if (qbase + fc * 16 + lg * 4 + i > qrow) p[i] = 0.0f;
      }
      *(f32x4*)&twbuf[w][lr][fc * 16 + lg * 4] = p;
      Wlo[fc] = cvtpk(p[0], p[1]);
      Whi[fc] = cvtpk(p[2], p[3]);
    }
#pragma unroll
    for (int ks = 0; ks < 2; ++ks) {
      unsigned int d0a = __shfl((int)Wlo[2 * ks], src0, 64);
      unsigned int d0b = __shfl((int)Wlo[2 * ks + 1], src0, 64);
      unsigned int d1a = __shfl((int)Whi[2 * ks], src0, 64);
      unsigned int d1b = __shfl((int)Whi[2 * ks + 1], src0, 64);
      unsigned int d2a = __shfl((int)Wlo[2 * ks], src1, 64);
      unsigned int d2b = __shfl((int)Wlo[2 * ks + 1], src1, 64);
      unsigned int d3a = __shfl((int)Whi[2 * ks], src1, 64);
      unsigned int d3b = __shfl((int)Whi[2 * ks + 1], src1, 64);
      unsigned int pd[4] = {hiFc ? d0b : d0a, hiFc ? d1b : d1a,
                            hiFc ? d2b : d2a, hiFc ? d3b : d3a};
      s16x8 pa = __builtin_bit_cast(s16x8, *(us8*)pd);
#pragma unroll
      for (int hc = 0; hc < 4; ++hc) {
        s16x8 vb = ldfrag(&ldsv[cb][(hc * 16 + lr) * 64 + (((ks * 4 + lg) ^ (lr & 7)) << 3)]);
        accpv[hc] = MFMA16(pa, vb, accpv[hc]);
      }
    }
    // coalesced transposed attn store, nontemporal (never re-read on device)
#pragma unroll
    for (int rr = 0; rr < 4; ++rr) {
      f32x4 v = *(const f32x4*)&twbuf[w][lg * 4 + rr][lr * 4];
      __builtin_nontemporal_store(
          v, (f32x4*)(attn_h + (size_t)(qbase + w * 16 + lg * 4 + rr) * S + kt * 64 + lr * 4));
    }
  };

  loadK(kA, 0);
  vdma(0, 0);
  {
    int kt = 0;
    while (true) {
      __syncthreads();  // drains DMA+prefetch: V(kt)+K(kt) ready; V buf kt^1 free
      if (kt < qt) { vdma(kt + 1, (kt + 1) & 1); loadK(kB, kt + 1); }
      p2body(kA, kt);
      if (++kt > qt) break;
      __syncthreads();
      if (kt < qt) { vdma(kt + 1, (kt + 1) & 1); loadK(kA, kt + 1); }
      p2body(kB, kt);
      if (++kt > qt) break;
    }
  }

  // ---------------- zero-fill strictly-upper region (nontemporal) ----------
  const int zstart = (qt + 1) * 64;
  if (zstart < S) {
    const int n4 = (S - zstart) >> 2;
    const f32x4 z = (f32x4){0.f, 0.f, 0.f, 0.f};
    for (int r = 0; r < 64; ++r) {
      float* dst = attn_h + (size_t)(qbase + r) * S + zstart;
      for (int i = t; i < n4; i += 256)
        __builtin_nontemporal_store(z, (f32x4*)(dst + i * 4));
    }
  }

  // ---------------- ctx write: [B*S][1024] bf16, granule-swizzled ----------
#pragma unroll
  for (int hc = 0; hc < 4; ++hc)
#pragma unroll
    for (int i = 0; i < 4; ++i) {
      int mr = b * S + qbase + w * 16 + lg * 4 + i;
      int nh = hd * 64 + hc * 16 + lr;
      int kg = nh >> 3, el = nh & 7;
      int kgp = (kg & ~7) | ((kg ^ mr) & 7);
      ctx[(size_t)mr * 1024 + kgp * 8 + el] = f2bf(accpv[hc][i]);
    }
}

// ---------------------------------------------------------------------------
extern "C" void kernel_launch(void* const* d_in, const int* in_sizes, int n_in,
                              void* d_out, int out_size, void* d_ws, size_t ws_size,
                              hipStream_t stream) {
  (void)in_sizes; (void)n_in; (void)out_size; (void)ws_size;
  const float* v_in = (const float*)d_in[0];
  const float* k_in = (const float*)d_in[1];
  const float* q_in = (const float*)d_in[2];
  const float* Wq = (const float*)d_in[4];
  const float* Wk = (const float*)d_in[5];
  const float* Wv = (const float*)d_in[6];
  const float* Wo = (const float*)d_in[7];

  float* out = (float*)d_out;
  float* attn = out + (size_t)2 * 2048 * 1024;

  unsigned short* ws = (unsigned short*)d_ws;
  const size_t MK = (size_t)4096 * 1024;
  const size_t WK = (size_t)1024 * 1024;
  unsigned short* qbfA = ws;
  unsigned short* kbfA = ws + MK;
  unsigned short* vbfA = ws + 2 * MK;
  unsigned short* WqT = ws + 3 * MK;
  unsigned short* WkT = WqT + WK;
  unsigned short* WvT = WkT + WK;
  unsigned short* WoT = WvT + WK;
  unsigned short* q_ws = WoT + WK;   // Q fragment-order tiles
  unsigned short* k_ws = q_ws + MK;  // K fragment-order tiles
  unsigned short* v_ws = k_ws + MK;  // V tiled layout
  unsigned short* ctx_ws = v_ws + MK;

  conv_k<<<7168, 256, 0, stream>>>(q_in, k_in, v_in, qbfA, kbfA, vbfA,
                                   Wq, Wk, Wv, Wo, WqT, WkT, WvT, WoT);
  qkv_gemm<<<dim3(256, 1, 3), 256, 0, stream>>>(qbfA, kbfA, vbfA, WqT, WkT, WvT,
                                                q_ws, k_ws, v_ws);
  attn_k<<<1024, 256, 0, stream>>>(q_ws, k_ws, v_ws, attn, ctx_ws);
  gemmWo<<<512, 256, 0, stream>>>(ctx_ws, WoT, out);
}

// Round 13
// 206.599 us; speedup vs baseline: 1.1947x; 1.0071x over previous
//
#include <hip/hip_runtime.h>
#include <hip/hip_bf16.h>
#include <cstdint>

// MHA with full attn-matrix output.  B=2 S=2048 D=1024 N=16 H=64.
// d_out = [out (B,S,D) fp32 | attn (B,N,S,S) fp32]

typedef __attribute__((ext_vector_type(4))) float f32x4;
typedef __attribute__((ext_vector_type(8))) short s16x8;
typedef __attribute__((ext_vector_type(8))) unsigned short us8;
typedef __attribute__((ext_vector_type(4))) unsigned short us4;

#define MFMA16(a, b, c) __builtin_amdgcn_mfma_f32_16x16x32_bf16((a), (b), (c), 0, 0, 0)
constexpr float L2E = 1.4426950408889634f;

__device__ __forceinline__ unsigned short f2bf(float f) {
  unsigned int u = __builtin_bit_cast(unsigned int, f);
  u += 0x7FFFu + ((u >> 16) & 1u);  // RNE
  return (unsigned short)(u >> 16);
}
__device__ __forceinline__ unsigned int cvtpk(float lo, float hi) {
  unsigned int r;
  asm("v_cvt_pk_bf16_f32 %0, %1, %2" : "=v"(r) : "v"(lo), "v"(hi));
  return r;
}
__device__ __forceinline__ s16x8 ldfrag(const unsigned short* p) {
  return __builtin_bit_cast(s16x8, *(const us8*)p);
}
// lds dest MUST be wave-uniform; per-lane part goes in g.
__device__ __forceinline__ void gload16(const void* g, void* l) {
  auto* gp = reinterpret_cast<const __attribute__((address_space(1))) unsigned int*>(
      reinterpret_cast<uintptr_t>(g));
  auto* lp = reinterpret_cast<__attribute__((address_space(3))) unsigned int*>(
      reinterpret_cast<uintptr_t>(l));
  __builtin_amdgcn_global_load_lds(gp, lp, 16, 0, 0);
}

// ---------------------------------------------------------------------------
// Merged conversion kernel.  Blocks [0,6144): inputs fp32->bf16 granule-swz.
// Blocks [6144,7168): weights transpose+convert+swz.
// ---------------------------------------------------------------------------
__global__ __launch_bounds__(256) void conv_k(
    const float* __restrict__ s0, const float* __restrict__ s1,
    const float* __restrict__ s2, unsigned short* __restrict__ d0,
    unsigned short* __restrict__ d1, unsigned short* __restrict__ d2,
    const float* __restrict__ w0, const float* __restrict__ w1,
    const float* __restrict__ w2, const float* __restrict__ w3,
    unsigned short* __restrict__ o0, unsigned short* __restrict__ o1,
    unsigned short* __restrict__ o2, unsigned short* __restrict__ o3) {
  const int blk = blockIdx.x;
  const int t = threadIdx.x;
  __shared__ float tile[64][65];
  if (blk < 6144) {
    const int y = blk >> 11, x = blk & 2047;
    const float* s = y == 0 ? s0 : (y == 1 ? s1 : s2);
    unsigned short* d = y == 0 ? d0 : (y == 1 ? d1 : d2);
    int gid = x * 256 + t;
    int m = gid >> 7, kg = gid & 127;
    f32x4 a = *(const f32x4*)(s + (size_t)m * 1024 + kg * 8);
    f32x4 b = *(const f32x4*)(s + (size_t)m * 1024 + kg * 8 + 4);
    us8 o;
#pragma unroll
    for (int j = 0; j < 4; ++j) { o[j] = f2bf(a[j]); o[j + 4] = f2bf(b[j]); }
    int kgp = (kg & ~7) | ((kg ^ m) & 7);
    *(us8*)(d + (size_t)m * 1024 + kgp * 8) = o;
  } else {
    const int r = blk - 6144;
    const int y = r >> 8, x = r & 255;
    const float* W = y == 0 ? w0 : (y == 1 ? w1 : (y == 2 ? w2 : w3));
    unsigned short* O = y == 0 ? o0 : (y == 1 ? o1 : (y == 2 ? o2 : o3));
    const int r0 = (x & 15) * 64, c0 = (x >> 4) * 64;
    {
      int rr = t >> 2, cq = (t & 3) * 16;
#pragma unroll
      for (int j = 0; j < 4; ++j) {
        f32x4 v = *(const f32x4*)(W + (size_t)(r0 + rr) * 1024 + c0 + cq + j * 4);
#pragma unroll
        for (int e = 0; e < 4; ++e) tile[rr][cq + j * 4 + e] = v[e];
      }
    }
    __syncthreads();
    int orow = t >> 2;
    int gr = c0 + orow;
#pragma unroll
    for (int gi = 0; gi < 2; ++gi) {
      int dl = (t & 3) * 16 + gi * 8;
      us8 o;
#pragma unroll
      for (int j = 0; j < 8; ++j) o[j] = f2bf(tile[dl + j][orow]);
      int kg = (r0 + dl) >> 3;
      int kgp = (kg & ~7) | ((kg ^ gr) & 7);
      *(us8*)(O + (size_t)gr * 1024 + kgp * 8) = o;
    }
  }
}

// ---------------------------------------------------------------------------
// Fused QKV projection GEMM, XCD-chunked dispatch, LDS-transpose epilogue.
// z==0: Q -> MFMA-fragment order (scaled 1/8).   z==1: K -> fragment order.
// z==2: V -> per-64-tile layout [h][g^(h&7)][s&7].
// Block output = 4 contiguous 8KB sub-tiles -> scatter to LDS, stream 16B.
// ---------------------------------------------------------------------------
__global__ __launch_bounds__(256) void qkv_gemm(
    const unsigned short* __restrict__ Aq, const unsigned short* __restrict__ Ak,
    const unsigned short* __restrict__ Av, const unsigned short* __restrict__ Bq,
    const unsigned short* __restrict__ Bk, const unsigned short* __restrict__ Bv,
    unsigned short* __restrict__ Oq, unsigned short* __restrict__ Ok,
    unsigned short* __restrict__ Ov) {
  const int z = blockIdx.z;
  const unsigned short* A = z == 0 ? Aq : (z == 1 ? Ak : Av);
  const unsigned short* Bt = z == 0 ? Bq : (z == 1 ? Bk : Bv);

  __shared__ __align__(16) unsigned short lds[16384];
  const int t = threadIdx.x, w = t >> 6, lane = t & 63;
  const int lr = lane & 15, lg = lane >> 4;
  const int wr = (w >> 1) * 64, wc = (w & 1) * 64;
  const int xf = blockIdx.x;                    // 256 blocks, XCD-chunked
  const int nfb = (xf & 7) * 32 + (xf >> 3);    // each XCD: 4 A-rows x 8 B-cols
  const int m0 = (nfb >> 3) * 128, n0 = (nfb & 7) * 128;
  const int srow = w * 32 + (lane >> 3), sg = lane & 7;

  f32x4 acc[4][4];
#pragma unroll
  for (int i = 0; i < 4; ++i)
#pragma unroll
    for (int j = 0; j < 4; ++j) acc[i][j] = (f32x4){0.f, 0.f, 0.f, 0.f};

  for (int k0 = 0; k0 < 1024; k0 += 64) {
#pragma unroll
    for (int q = 0; q < 4; ++q)
      gload16(A + (size_t)(m0 + srow + q * 8) * 1024 + k0 + sg * 8,
              &lds[(w * 32 + q * 8) * 64]);
#pragma unroll
    for (int q = 0; q < 4; ++q)
      gload16(Bt + (size_t)(n0 + srow + q * 8) * 1024 + k0 + sg * 8,
              &lds[8192 + (w * 32 + q * 8) * 64]);
    __syncthreads();
#pragma unroll
    for (int r2 = 0; r2 < 2; ++r2) {
      const int koff = ((r2 * 4 + lg) ^ (lr & 7)) * 8;
      s16x8 af[4], bfr[4];
#pragma unroll
      for (int x = 0; x < 4; ++x) af[x] = ldfrag(&lds[(wr + x * 16 + lr) * 64 + koff]);
#pragma unroll
      for (int x = 0; x < 4; ++x) bfr[x] = ldfrag(&lds[8192 + (wc + x * 16 + lr) * 64 + koff]);
#pragma unroll
      for (int am = 0; am < 4; ++am)
#pragma unroll
        for (int bn = 0; bn < 4; ++bn) acc[am][bn] = MFMA16(af[am], bfr[bn], acc[am][bn]);
    }
    __syncthreads();
  }

  // ---- epilogue: scatter to LDS (4 x 4096-u16 sub-tiles), stream out ----
  const float scale = z == 0 ? 0.125f : 1.0f;
#pragma unroll
  for (int am = 0; am < 4; ++am)
#pragma unroll
    for (int bn = 0; bn < 4; ++bn)
#pragma unroll
      for (int i = 0; i < 4; ++i) {
        int grl = wr + am * 16 + lg * 4 + i;  // local row 0..127  (= ss low bits)
        int gcl = wc + bn * 16 + lr;          // local col 0..127  (= hh low bits)
        int st = grl >> 6, s6 = grl & 63;
        int hd2 = gcl >> 6, h6 = gcl & 63;
        int off;
        if (z < 2)
          off = ((s6 >> 4) & 3) * 1024 + (h6 >> 5) * 512 +
                (((h6 >> 3) & 3) * 16 + (s6 & 15)) * 8 + (h6 & 7);
        else
          off = h6 * 64 + ((((s6 >> 3) & 7) ^ (h6 & 7)) << 3) + (s6 & 7);
        lds[(st * 2 + hd2) * 4096 + off] = f2bf(acc[am][bn][i] * scale);
      }
  __syncthreads();
  unsigned short* C = z == 0 ? Oq : (z == 1 ? Ok : Ov);
  const int bb = m0 >> 11, t0 = (m0 & 2047) >> 6, nn0 = n0 >> 6;
#pragma unroll
  for (int c = 0; c < 8; ++c) {
    int g = c * 256 + t;  // granule 0..2047 (8 u16 each)
    int sub = g >> 9, inner = g & 511;
    int st = sub >> 1, hd2 = sub & 1;
    size_t dst = ((size_t)(bb * 16 + nn0 + hd2)) * 131072 + (size_t)(t0 + st) * 4096 +
                 (size_t)inner * 8;
    *(us8*)(C + dst) = *(const us8*)&lds[g * 8];
  }
}

// ---------------------------------------------------------------------------
// Wo GEMM: out[4096,1024] fp32 = ctx(bf16 swz) * WoT.  128x64 tile, 512 blk,
// XCD-chunked dispatch, nontemporal out stores.
// ---------------------------------------------------------------------------
__global__ __launch_bounds__(256) void gemmWo(const unsigned short* __restrict__ A,
                                              const unsigned short* __restrict__ Bt,
                                              float* __restrict__ C) {
  __shared__ __align__(16) unsigned short lds[12288];
  const int t = threadIdx.x, w = t >> 6, lane = t & 63;
  const int lr = lane & 15, lg = lane >> 4;
  const int wr = (w >> 1) * 64, wc = (w & 1) * 32;
  const int xf = blockIdx.x;                    // 512 blocks
  const int nfb = (xf & 7) * 64 + (xf >> 3);    // each XCD: 4 A-rows x 16 B-cols
  const int m0 = (nfb >> 4) * 128, n0 = (nfb & 15) * 64;

  f32x4 acc[4][2];
#pragma unroll
  for (int i = 0; i < 4; ++i)
#pragma unroll
    for (int j = 0; j < 2; ++j) acc[i][j] = (f32x4){0.f, 0.f, 0.f, 0.f};

  for (int k0 = 0; k0 < 1024; k0 += 64) {
#pragma unroll
    for (int q = 0; q < 4; ++q)
      gload16(A + (size_t)(m0 + w * 32 + q * 8 + (lane >> 3)) * 1024 + k0 + (lane & 7) * 8,
              &lds[(w * 32 + q * 8) * 64]);
#pragma unroll
    for (int q = 0; q < 2; ++q)
      gload16(Bt + (size_t)(n0 + w * 16 + q * 8 + (lane >> 3)) * 1024 + k0 + (lane & 7) * 8,
              &lds[8192 + (w * 16 + q * 8) * 64]);
    __syncthreads();
#pragma unroll
    for (int r2 = 0; r2 < 2; ++r2) {
      const int koff = ((r2 * 4 + lg) ^ (lr & 7)) * 8;
      s16x8 af[4], bfr[2];
#pragma unroll
      for (int x = 0; x < 4; ++x) af[x] = ldfrag(&lds[(wr + x * 16 + lr) * 64 + koff]);
#pragma unroll
      for (int x = 0; x < 2; ++x) bfr[x] = ldfrag(&lds[8192 + (wc + x * 16 + lr) * 64 + koff]);
#pragma unroll
      for (int am = 0; am < 4; ++am)
#pragma unroll
        for (int bn = 0; bn < 2; ++bn) acc[am][bn] = MFMA16(af[am], bfr[bn], acc[am][bn]);
    }
    __syncthreads();
  }
#pragma unroll
  for (int am = 0; am < 4; ++am)
#pragma unroll
    for (int bn = 0; bn < 2; ++bn)
#pragma unroll
      for (int i = 0; i < 4; ++i) {
        int gr = m0 + wr + am * 16 + lg * 4 + i;
        int gc = n0 + wc + bn * 16 + lr;
        __builtin_nontemporal_store(acc[am][bn][i], &C[(size_t)gr * 1024 + gc]);
      }
}

// ---------------------------------------------------------------------------
// Fused causal attention, swapped-QK.  Block=(b,head,64 q-rows), 4 waves.
// Q/K in fragment-order global layout (lane-contiguous 1KB bursts, no LDS).
// K software-pipelined into registers (2-state kA/kB).  Max-free softmax.
// V DMA-staged double-buffered.  Zero-fill of the strictly-upper region is
// INTERLEAVED into pass 1 (store-idle phase) to flatten HBM write BW.
// attn + zero stores NONTEMPORAL.
// ---------------------------------------------------------------------------
__global__ __launch_bounds__(256) void attn_k(const unsigned short* __restrict__ qw,
                                              const unsigned short* __restrict__ kw,
                                              const unsigned short* __restrict__ vw,
                                              float* __restrict__ attn,
                                              unsigned short* __restrict__ ctx) {
  constexpr int S = 2048, N = 16;
  const int flat = blockIdx.x;
  const int nf = (flat & 7) * 128 + (flat >> 3);  // XCD-chunked
  const int qt = 31 - (nf & 31);                  // heaviest blocks first
  const int hd = (nf >> 5) & 15, b = nf >> 9;
  const int qbase = qt * 64;
  const int t = threadIdx.x, w = t >> 6, lane = t & 63;
  const int lr = lane & 15, lg = lane >> 4;
  const size_t headoff = ((size_t)(b * N + hd)) * S * 64;
  const unsigned short* qh = qw + headoff;  // fragment-order tiles
  const unsigned short* kh = kw + headoff;  // fragment-order tiles
  const unsigned short* vh = vw + headoff;  // tiled V
  float* attn_h = attn + ((size_t)(b * N + hd)) * S * S;
  const int qrow = qbase + w * 16 + lr;

  __shared__ __align__(16) unsigned short ldsv[2][4096];
  __shared__ __align__(16) float twbuf[4][16][76];

  s16x8 qf0 = ldfrag(qh + (size_t)qt * 4096 + w * 1024 + lane * 8);
  s16x8 qf1 = ldfrag(qh + (size_t)qt * 4096 + w * 1024 + 512 + lane * 8);

  s16x8 kA[8], kB[8];
  auto loadK = [&](s16x8(&kf)[8], int kt) {
    const unsigned short* kb = kh + (size_t)kt * 4096;
#pragma unroll
    for (int fc = 0; fc < 4; ++fc) {
      kf[fc * 2] = ldfrag(kb + fc * 1024 + lane * 8);
      kf[fc * 2 + 1] = ldfrag(kb + fc * 1024 + 512 + lane * 8);
    }
  };

  // ---------------- pass 1: exp-sum + interleaved zero-fill ----------------
  const int Z = 31 - qt;       // zero tiles (64x64) to write
  const int zcol0 = (qt + 1) * 64;
  int zdone = 0;
  const int zrow = t >> 2;     // thread's row within a zero tile (x4 stores)
  float lsum = 0.f;
  auto p1body = [&](s16x8(&kf)[8], int kt) {
    float ts = 0.f;
#pragma unroll
    for (int fc = 0; fc < 4; ++fc) {
      f32x4 a = (f32x4){0.f, 0.f, 0.f, 0.f};
      a = MFMA16(kf[fc * 2], qf0, a);
      a = MFMA16(kf[fc * 2 + 1], qf1, a);
      if (kt == qt) {
#pragma unroll
        for (int i = 0; i < 4; ++i)
          if (qbase + fc * 16 + lg * 4 + i > qrow) a[i] = -3.0e38f;
      }
#pragma unroll
      for (int i = 0; i < 4; ++i) ts += __builtin_amdgcn_exp2f(a[i] * L2E);
    }
    lsum += ts;
    // proportional share of zero tiles for this iteration (store-idle phase)
    const int ztarget = ((kt + 1) * Z) / (qt + 1);
    const f32x4 zv = (f32x4){0.f, 0.f, 0.f, 0.f};
    for (; zdone < ztarget; ++zdone) {
      float* dst = attn_h + (size_t)(qbase + zrow) * S + zcol0 + zdone * 64;
#pragma unroll
      for (int j = 0; j < 4; ++j) {
        // rows zrow + 64*j/... : 256 threads x 4 = 1024 f32x4 = 64x64 floats
        int idx = j * 256 + t, row = idx >> 4, c4 = (idx & 15) * 4;
        __builtin_nontemporal_store(
            zv, (f32x4*)(attn_h + (size_t)(qbase + row) * S + zcol0 + zdone * 64 + c4));
      }
      (void)dst;
    }
  };
  loadK(kA, 0);
  {
    int kt = 0;
    while (true) {
      if (kt < qt) loadK(kB, kt + 1);
      p1body(kA, kt);
      if (++kt > qt) break;
      if (kt < qt) loadK(kA, kt + 1);
      p1body(kB, kt);
      if (++kt > qt) break;
    }
  }
  lsum += __shfl_xor(lsum, 16);
  lsum += __shfl_xor(lsum, 32);
  const float c0 = -__builtin_amdgcn_logf(lsum);  // v_log_f32=log2; p=exp2(s*L2E+c0)

  // ---------------- pass 2: attn write + PV (pipelined) ----------------
  f32x4 accpv[4];
#pragma unroll
  for (int i = 0; i < 4; ++i) accpv[i] = (f32x4){0.f, 0.f, 0.f, 0.f};
  const int src0 = lr + 32 * (lg & 1), src1 = src0 + 16;
  const bool hiFc = (lg >> 1) & 1;

  auto vdma = [&](int kt, int buf) {
    const unsigned short* vsrc = vh + (size_t)kt * 4096;
    gload16(vsrc + (w * 128 + lane) * 8, &ldsv[buf][w * 1024]);
    gload16(vsrc + (w * 128 + 64 + lane) * 8, &ldsv[buf][w * 1024 + 512]);
  };

  auto p2body = [&](s16x8(&kf)[8], int kt) {
    const int cb = kt & 1;
    f32x4 s[4];
#pragma unroll
    for (int fc = 0; fc < 4; ++fc) {
      f32x4 a = (f32x4){0.f, 0.f, 0.f, 0.f};
      a = MFMA16(kf[fc * 2], qf0, a);
      a = MFMA16(kf[fc * 2 + 1], qf1, a);
      s[fc] = a;
    }
    unsigned int Wlo[4], Whi[4];
#pragma unroll
    for (int fc = 0; fc < 4; ++fc) {
      f32x4 p;
#pragma unroll
      for (int i = 0; i < 4; ++i)
        p[i] = __builtin_amdgcn_exp2f(__builtin_fmaf(s[fc][i], L2E, c0));
      if (kt == qt) {
#pragma unroll
        for (int i = 0; i < 4; ++i)
          if (qbase + fc * 16 + lg * 4 + i > qrow) p[i] = 0.0f;
      }
      *(f32x4*)&twbuf[w][lr][fc * 16 + lg * 4] = p;
      Wlo[fc] = cvtpk(p[0], p[1]);
      Whi[fc] = cvtpk(p[2], p[3]);
    }
#pragma unroll
    for (int ks = 0; ks < 2; ++ks) {
      unsigned int d0a = __shfl((int)Wlo[2 * ks], src0, 64);
      unsigned int d0b = __shfl((int)Wlo[2 * ks + 1], src0, 64);
      unsigned int d1a = __shfl((int)Whi[2 * ks], src0, 64);
      unsigned int d1b = __shfl((int)Whi[2 * ks + 1], src0, 64);
      unsigned int d2a = __shfl((int)Wlo[2 * ks], src1, 64);
      unsigned int d2b = __shfl((int)Wlo[2 * ks + 1], src1, 64);
      unsigned int d3a = __shfl((int)Whi[2 * ks], src1, 64);
      unsigned int d3b = __shfl((int)Whi[2 * ks + 1], src1, 64);
      unsigned int pd[4] = {hiFc ? d0b : d0a, hiFc ? d1b : d1a,
                            hiFc ? d2b : d2a, hiFc ? d3b : d3a};
      s16x8 pa = __builtin_bit_cast(s16x8, *(us8*)pd);
#pragma unroll
      for (int hc = 0; hc < 4; ++hc) {
        s16x8 vb = ldfrag(&ldsv[cb][(hc * 16 + lr) * 64 + (((ks * 4 + lg) ^ (lr & 7)) << 3)]);
        accpv[hc] = MFMA16(pa, vb, accpv[hc]);
      }
    }
    // coalesced transposed attn store, nontemporal (never re-read on device)
#pragma unroll
    for (int rr = 0; rr < 4; ++rr) {
      f32x4 v = *(const f32x4*)&twbuf[w][lg * 4 + rr][lr * 4];
      __builtin_nontemporal_store(
          v, (f32x4*)(attn_h + (size_t)(qbase + w * 16 + lg * 4 + rr) * S + kt * 64 + lr * 4));
    }
  };

  loadK(kA, 0);
  vdma(0, 0);
  {
    int kt = 0;
    while (true) {
      __syncthreads();  // drains DMA+prefetch: V(kt)+K(kt) ready; V buf kt^1 free
      if (kt < qt) { vdma(kt + 1, (kt + 1) & 1); loadK(kB, kt + 1); }
      p2body(kA, kt);
      if (++kt > qt) break;
      __syncthreads();
      if (kt < qt) { vdma(kt + 1, (kt + 1) & 1); loadK(kA, kt + 1); }
      p2body(kB, kt);
      if (++kt > qt) break;
    }
  }

  // ---------------- ctx write: [B*S][1024] bf16, granule-swizzled ----------
#pragma unroll
  for (int hc = 0; hc < 4; ++hc)
#pragma unroll
    for (int i = 0; i < 4; ++i) {
      int mr = b * S + qbase + w * 16 + lg * 4 + i;
      int nh = hd * 64 + hc * 16 + lr;
      int kg = nh >> 3, el = nh & 7;
      int kgp = (kg & ~7) | ((kg ^ mr) & 7);
      ctx[(size_t)mr * 1024 + kgp * 8 + el] = f2bf(accpv[hc][i]);
    }
}

// ---------------------------------------------------------------------------
extern "C" void kernel_launch(void* const* d_in, const int* in_sizes, int n_in,
                              void* d_out, int out_size, void* d_ws, size_t ws_size,
                              hipStream_t stream) {
  (void)in_sizes; (void)n_in; (void)out_size; (void)ws_size;
  const float* v_in = (const float*)d_in[0];
  const float* k_in = (const float*)d_in[1];
  const float* q_in = (const float*)d_in[2];
  const float* Wq = (const float*)d_in[4];
  const float* Wk = (const float*)d_in[5];
  const float* Wv = (const float*)d_in[6];
  const float* Wo = (const float*)d_in[7];

  float* out = (float*)d_out;
  float* attn = out + (size_t)2 * 2048 * 1024;

  unsigned short* ws = (unsigned short*)d_ws;
  const size_t MK = (size_t)4096 * 1024;
  const size_t WK = (size_t)1024 * 1024;
  unsigned short* qbfA = ws;
  unsigned short* kbfA = ws + MK;
  unsigned short* vbfA = ws + 2 * MK;
  unsigned short* WqT = ws + 3 * MK;
  unsigned short* WkT = WqT + WK;
  unsigned short* WvT = WkT + WK;
  unsigned short* WoT = WvT + WK;
  unsigned short* q_ws = WoT + WK;   // Q fragment-order tiles
  unsigned short* k_ws = q_ws + MK;  // K fragment-order tiles
  unsigned short* v_ws = k_ws + MK;  // V tiled layout
  unsigned short* ctx_ws = v_ws + MK;

  conv_k<<<7168, 256, 0, stream>>>(q_in, k_in, v_in, qbfA, kbfA, vbfA,
                                   Wq, Wk, Wv, Wo, WqT, WkT, WvT, WoT);
  qkv_gemm<<<dim3(256, 1, 3), 256, 0, stream>>>(qbfA, kbfA, vbfA, WqT, WkT, WvT,
                                                q_ws, k_ws, v_ws);
  attn_k<<<1024, 256, 0, stream>>>(q_ws, k_ws, v_ws, attn, ctx_ws);
  gemmWo<<<512, 256, 0, stream>>>(ctx_ws, WoT, out);
}